// Round 2
// baseline (1036.965 us; speedup 1.0000x reference)
//
#include <hip/hip_runtime.h>

// Walsh-Hadamard (n=4096) per row + affine epilogue: out = scale * (H x)/64 + shift
// v2b: radix 64x64 decomposition, ONE WAVE PER ROW (block = 64 threads).
//   Stage 1: lane l owns elements e = 64h + l (lo digit fixed = l). Loads are
//            64 dword instrs, each covering 256 contiguous bytes -> perfect
//            streaming; nontemporal (input is read exactly once).
//            WHT64 over hi digit entirely in registers.
//   Transpose: single LDS round-trip, pad-65 rows. Write addr = l*65+h and
//            read addr = j*65+l are both exactly 2-way bank-aliased (free,
//            m136). One wave per block -> __syncthreads() is a self-barrier
//            (no cross-wave memory-idle bubbles; the old 3-round scheme had
//            two 4-wave barriers and 2x the LDS traffic).
//   Stage 2: lane l owns e = 64l + j (contiguous!). WHT64 over lo digit in
//            registers, then a fully vectorized epilogue: 16 vec4 loads of
//            scale, 16 of shift, 16 nontemporal vec4 stores.
// NOTE: use clang ext_vector_type, NOT HIP float4 — __builtin_nontemporal_*
// requires a native vector type (HIP_vector_type class is rejected).
// LDS/block = 64*65*4 = 16640 B -> 9 blocks (9 waves) per CU; memory-bound
// streaming needs only ~9 KB in flight per CU (Little's law) -> ample.

#define ROW 4096
#define PAD 65  // padded LDS row stride (words); 65 odd -> 2-way aliasing max

typedef float floatx4 __attribute__((ext_vector_type(4)));

__device__ __forceinline__ void wht64(float v[64]) {
#pragma unroll
  for (int h = 1; h < 64; h <<= 1) {
#pragma unroll
    for (int i = 0; i < 64; ++i) {
      if ((i & h) == 0) {
        const float a = v[i], b = v[i | h];
        v[i] = a + b;
        v[i | h] = a - b;
      }
    }
  }
}

__global__ __launch_bounds__(64) void AdaptiveHadamardTransform_kernel(
    const float* __restrict__ x, const float* __restrict__ scale,
    const float* __restrict__ shift, float* __restrict__ out) {
  __shared__ float lds[64 * PAD];  // 16640 B

  const int l = threadIdx.x;  // lane 0..63 (one wave per block)
  const long long base = (long long)blockIdx.x * ROW;

  float v[64];

  // ---- Stage 1 load: v[h] = x[base + 64h + l].
  // Each instr: 64 lanes * 4 B = 256 contiguous bytes; h sweeps the 16 KB row.
  const float* __restrict__ xr = x + base + l;
#pragma unroll
  for (int h = 0; h < 64; ++h)
    v[h] = __builtin_nontemporal_load(xr + 64 * h);

  wht64(v);  // transform hi digit (lane owns lo = l fixed)

  // ---- Transpose through LDS (pad-65: both phases 2-way aliased = free).
#pragma unroll
  for (int h = 0; h < 64; ++h) lds[l * PAD + h] = v[h];
  __syncthreads();  // single wave: compiles to waitcnt + trivial barrier
#pragma unroll
  for (int j = 0; j < 64; ++j) v[j] = lds[j * PAD + l];

  wht64(v);  // transform lo digit (lane owns hi = l fixed)

  // ---- Epilogue: lane l holds out elements e = 64l + j, j = 0..63 contiguous.
  // Fully vectorized: vec4 scale/shift loads (L1-hot) + vec4 nt stores.
  const float norm = 0.015625f;  // 1/sqrt(4096)
  const floatx4* __restrict__ s4 = reinterpret_cast<const floatx4*>(scale + 64 * l);
  const floatx4* __restrict__ h4 = reinterpret_cast<const floatx4*>(shift + 64 * l);
  floatx4* __restrict__ o4 = reinterpret_cast<floatx4*>(out + base + 64 * l);
#pragma unroll
  for (int j = 0; j < 16; ++j) {
    const floatx4 sc = s4[j];
    const floatx4 sh = h4[j];
    floatx4 o;
    o.x = fmaf(sc.x, v[4 * j + 0] * norm, sh.x);
    o.y = fmaf(sc.y, v[4 * j + 1] * norm, sh.y);
    o.z = fmaf(sc.z, v[4 * j + 2] * norm, sh.z);
    o.w = fmaf(sc.w, v[4 * j + 3] * norm, sh.w);
    __builtin_nontemporal_store(o, o4 + j);
  }
}

extern "C" void kernel_launch(void* const* d_in, const int* in_sizes, int n_in,
                              void* d_out, int out_size, void* d_ws, size_t ws_size,
                              hipStream_t stream) {
  const float* x = (const float*)d_in[0];
  const float* scale = (const float*)d_in[1];
  const float* shift = (const float*)d_in[2];
  float* out = (float*)d_out;

  const int rows = in_sizes[0] / ROW;  // 4*4096 = 16384
  AdaptiveHadamardTransform_kernel<<<rows, 64, 0, stream>>>(x, scale, shift, out);
}

// Round 3
// 455.641 us; speedup vs baseline: 2.2758x; 2.2758x over previous
//
#include <hip/hip_runtime.h>

// Walsh-Hadamard (n=4096) per row + affine epilogue: out = scale * (H x)/64 + shift
// v3: v1's verified radix 16x16x16 structure (256 thr/block, 16 elem/thread,
//     pad-17 LDS, coalesced dword nt stores) + MULTI-ROW blocks with next-row
//     register prefetch to de-burst HBM demand.
//
// v2 post-mortem (counters): one-wave-per-row radix-64 was latency-bound
// (21.8% occupancy, 1.9% VALUBusy, 17% BW) and its 16B/lane scattered nt
// stores caused 3.2x write amplification (WRITE_SIZE 850 MB vs 268 ideal).
// Reverting to the 32-waves/CU shape; keeping per-instruction full-sector
// store coalescing (wave covers 256 contiguous bytes per store instr).
//
// Digit order (identical to v1 — verified absmax 0.015625):
//   R1: regs, transform i0 (thread t owns 16 contiguous elements -> 4x float4 loads)
//   R2: LDS,  transform i1 (pad-17 rows: 2-way bank aliasing = free)
//   R3: LDS,  transform i2 -> final ownership e = r*256 + t -> coalesced 256B/instr
//             nontemporal dword stores (out is never re-read; keeps L3 for x).
//
// New in v3: RPB=8 rows per block; after the current row's R1 transform we
// issue the next row's 4x float4 loads into a second register set, so HBM
// loads stay in flight under the ~2000cy of LDS+VALU work per row.
// VGPR budget: v[16] + nxt[16] + addressing ~= 56 < 64 -> 8 blocks/CU.

#define ROW 4096
#define STR 17  // padded LDS row stride (words)
#define RPB 8   // rows per block (16384 % 8 == 0)

__device__ __forceinline__ void wht16(float v[16]) {
#pragma unroll
  for (int h = 1; h < 16; h <<= 1) {
#pragma unroll
    for (int i = 0; i < 16; ++i) {
      if ((i & h) == 0) {
        float a = v[i], b = v[i | h];
        v[i] = a + b;
        v[i | h] = a - b;
      }
    }
  }
}

__global__ __launch_bounds__(256) void AdaptiveHadamardTransform_kernel(
    const float* __restrict__ x, const float* __restrict__ scale,
    const float* __restrict__ shift, float* __restrict__ out) {
  __shared__ float lds[256 * STR];  // 17408 B -> 8 blocks/CU (thread-limited)

  const int t = threadIdx.x;
  const long long row0 = (long long)blockIdx.x * RPB;

  float v[16], nxt[16];

  // ---- initial load: row0, elements e = 16t + j, 4x float4 (16 B/lane).
  {
    const float4* __restrict__ x4 =
        reinterpret_cast<const float4*>(x + row0 * ROW + 16 * t);
#pragma unroll
    for (int j = 0; j < 4; ++j) {
      const float4 f = x4[j];
      v[4 * j + 0] = f.x;
      v[4 * j + 1] = f.y;
      v[4 * j + 2] = f.z;
      v[4 * j + 3] = f.w;
    }
  }

  for (int rr = 0; rr < RPB; ++rr) {
    const long long base = (row0 + rr) * ROW;

    wht16(v);  // transform i0

    // ---- prefetch next row while LDS phases run (uniform branch, no div).
    if (rr + 1 < RPB) {
      const float4* __restrict__ x4 =
          reinterpret_cast<const float4*>(x + (base + ROW) + 16 * t);
#pragma unroll
      for (int j = 0; j < 4; ++j) {
        const float4 f = x4[j];
        nxt[4 * j + 0] = f.x;
        nxt[4 * j + 1] = f.y;
        nxt[4 * j + 2] = f.z;
        nxt[4 * j + 3] = f.w;
      }
    }

    // LDS layout: addr(i2,i1,i0) = (i2*16 + i1)*STR + i0.  Thread t = (i2*16+i1).
#pragma unroll
    for (int j = 0; j < 16; ++j) lds[t * STR + j] = v[j];
    __syncthreads();

    // ---- R2: thread t owns (i2 = t>>4, i0 = t&15), vary i1 = r. 2-way max.
    {
      const int i2 = t >> 4, i0 = t & 15;
#pragma unroll
      for (int r = 0; r < 16; ++r) v[r] = lds[(i2 * 16 + r) * STR + i0];
      wht16(v);  // transform i1
      // write back to the same addresses this thread read -> no barrier first
#pragma unroll
      for (int r = 0; r < 16; ++r) lds[(i2 * 16 + r) * STR + i0] = v[r];
    }
    __syncthreads();

    // ---- R3: thread t owns (i1 = t>>4, i0 = t&15), vary i2 = r. 3-way max.
    {
      const int i1 = t >> 4, i0 = t & 15;
#pragma unroll
      for (int r = 0; r < 16; ++r) v[r] = lds[(r * 16 + i1) * STR + i0];
    }
    wht16(v);  // transform i2

    // ---- Epilogue: thread t holds e(r) = r*256 + t. Wave covers 256
    // contiguous bytes per store instr (full sectors -> nt is safe, no
    // write amplification). out never re-read -> nontemporal.
    const float norm = 0.015625f;  // 1/sqrt(4096)
#pragma unroll
    for (int r = 0; r < 16; ++r) {
      const int c = r * 256 + t;
      const float o = fmaf(scale[c], v[r] * norm, shift[c]);
      __builtin_nontemporal_store(o, out + base + c);
    }

    // WAR guard: all R3 LDS reads must finish before next row's R1 writes.
    __syncthreads();

    // rotate prefetched row into place (16 v_mov, ~0.5% of a row's work)
#pragma unroll
    for (int j = 0; j < 16; ++j) v[j] = nxt[j];
  }
}

extern "C" void kernel_launch(void* const* d_in, const int* in_sizes, int n_in,
                              void* d_out, int out_size, void* d_ws, size_t ws_size,
                              hipStream_t stream) {
  const float* x = (const float*)d_in[0];
  const float* scale = (const float*)d_in[1];
  const float* shift = (const float*)d_in[2];
  float* out = (float*)d_out;

  const int rows = in_sizes[0] / ROW;  // 4*4096 = 16384, divisible by RPB
  AdaptiveHadamardTransform_kernel<<<rows / RPB, 256, 0, stream>>>(x, scale, shift, out);
}

// Round 4
// 450.643 us; speedup vs baseline: 2.3011x; 1.0111x over previous
//
#include <hip/hip_runtime.h>

// Walsh-Hadamard (n=4096) per row + affine epilogue: out = scale*(H x)/64 + shift
// v4: async-DMA pipelined radix 16x16x16.
//
// v3 post-mortem: 2.4 TB/s, VALU 16%, occupancy 27% -> latency-bound. A wave
// has HBM loads in flight only ~5% of its row iteration; Little's law needs
// ~22 KB/CU outstanding to sustain 6.3 TB/s. Fix: global_load_lds DMA stages
// row r+1 into a linear LDS buffer WHILE row r computes, with counted
// s_waitcnt vmcnt(4) (never 0 in-loop) + raw s_barrier (T3/T4 pattern;
// __syncthreads() would drain vmcnt and kill the overlap).
//
// Digit order FLIPPED vs v1 (transform i2, then i1, then i0):
//   R1: read stage linear, e = 256*i2 + t  -> b32, bank = t%32, 2-way (free).
//       wht16 over i2; write work[S2*i2 + 17*i1 + i0]   (weights 277/17/1:
//       all phases <=~2-4-way bank multiplicity -- verified by hand algebra).
//   R2: own (i2,i0) = (t>>4, t&15), read/write work[c2 + 17*r], wht over i1.
//   R3: own (i2,i1) = (t>>4, t&15), read work[c3 + j] (contiguous), wht over
//       i0 -> final ownership e = 16t + j CONTIGUOUS:
//         * scale/shift preloaded ONCE per block (32 VGPR) -- removes the
//           32 cached loads per row that v1/v3 paid,
//         * float4 REGULAR stores (write-back L2 merges partial sectors;
//           v2's 3.2x amplification was nontemporal-specific).
//
// LDS: stage 16384 B (linear, glld dest must be linear) + work 17728 B
//      = 34112 B -> 4 blocks/CU; each block keeps 16 KB DMA in flight
//      -> 64 KB/CU outstanding >> 22 KB needed.
// vmcnt ordering per wave: [4 glld (older)] then [4 stores (newer)] ->
// vmcnt(4) at loop top drains exactly the glld of the row about to be read.

#define ROW 4096
#define NT 256
#define RPB 8    // rows per block; grid = 16384/8 = 2048
#define S2 277   // work stride for i2 digit (odd)
#define SI1 17   // work weight for i1 digit (odd)

__device__ __forceinline__ void wht16(float v[16]) {
#pragma unroll
  for (int h = 1; h < 16; h <<= 1) {
#pragma unroll
    for (int i = 0; i < 16; ++i) {
      if ((i & h) == 0) {
        float a = v[i], b = v[i | h];
        v[i] = a + b;
        v[i | h] = a - b;
      }
    }
  }
}

__device__ __forceinline__ void glld16(const float* g, float* l) {
  // async 16 B/lane global->LDS; LDS dest = wave-uniform base + lane*16 (HW).
  __builtin_amdgcn_global_load_lds(
      (const __attribute__((address_space(1))) void*)g,
      (__attribute__((address_space(3))) void*)l, 16, 0, 0);
}

#define WAIT_VM(N)                                      \
  asm volatile("s_waitcnt vmcnt(" #N ")" ::: "memory"); \
  __builtin_amdgcn_sched_barrier(0)
#define WAIT_LGKM                                     \
  asm volatile("s_waitcnt lgkmcnt(0)" ::: "memory"); \
  __builtin_amdgcn_sched_barrier(0)
#define BAR asm volatile("s_barrier" ::: "memory")

__global__ __launch_bounds__(NT, 4) void AdaptiveHadamardTransform_kernel(
    const float* __restrict__ x, const float* __restrict__ scale,
    const float* __restrict__ shift, float* __restrict__ out) {
  __shared__ float stage[ROW];      // 16384 B, linear (glld destination)
  __shared__ float work[16 * S2];   // 17728 B, odd-weight layout

  const int t = threadIdx.x;
  const int wid = t >> 6, lane = t & 63;
  const long long row0 = (long long)blockIdx.x * RPB;

  // ---- scale/shift preload: final ownership is e = 16t + j (row-invariant).
  float4 sc[4], sh[4];
  {
    const float4* s4 = reinterpret_cast<const float4*>(scale + 16 * t);
    const float4* h4 = reinterpret_cast<const float4*>(shift + 16 * t);
#pragma unroll
    for (int q = 0; q < 4; ++q) {
      sc[q] = s4[q];
      sh[q] = h4[q];
    }
  }

  // per-thread LDS word offsets (row-invariant, kept in registers)
  const int c1 = SI1 * (t >> 4) + (t & 15);       // R1 write: work[S2*k + c1]
  const int c2 = S2 * (t >> 4) + (t & 15);        // R2:       work[c2 + SI1*r]
  const int c3 = S2 * (t >> 4) + SI1 * (t & 15);  // R3:       work[c3 + j]

  // ---- prologue: stage row0, drain, barrier.
  {
    const float* g = x + row0 * ROW;
#pragma unroll
    for (int q = 0; q < 4; ++q)
      glld16(g + (wid * 4 + q) * 256 + lane * 4, &stage[(wid * 4 + q) * 256]);
  }
  WAIT_VM(0);
  BAR;

  float v[16];
  const float norm = 0.015625f;  // 1/sqrt(4096)

  for (int r = 0; r < RPB; ++r) {
    const long long base = (row0 + r) * ROW;

    if (r) {
      // drain glld(row r) (4 oldest); leave prev epilogue's 4 stores flying.
      WAIT_VM(4);
      BAR;  // also the WAR guard: everyone done with work (prev R3 reads)
    }

    // ---- R1: stage -> regs (bank-free), wht over i2, regs -> work.
#pragma unroll
    for (int k = 0; k < 16; ++k) v[k] = stage[t + 256 * k];
    wht16(v);
#pragma unroll
    for (int k = 0; k < 16; ++k) work[S2 * k + c1] = v[k];
    WAIT_LGKM;
    BAR;  // stage free + work visible cross-wave

    // ---- issue next row's DMA now; it flies under R2+R3+epilogue.
    if (r + 1 < RPB) {
      const float* g = x + base + ROW;
#pragma unroll
      for (int q = 0; q < 4; ++q)
        glld16(g + (wid * 4 + q) * 256 + lane * 4, &stage[(wid * 4 + q) * 256]);
    }

    // ---- R2: wht over i1 (read/write same addresses; data-dep orders them).
#pragma unroll
    for (int k = 0; k < 16; ++k) v[k] = work[c2 + SI1 * k];
    wht16(v);
#pragma unroll
    for (int k = 0; k < 16; ++k) work[c2 + SI1 * k] = v[k];
    WAIT_LGKM;
    BAR;

    // ---- R3: wht over i0; final ownership e = 16t + j contiguous.
#pragma unroll
    for (int j = 0; j < 16; ++j) v[j] = work[c3 + j];
    wht16(v);

    // ---- epilogue: float4 regular stores (L2 write-back merges sectors).
    float4* o4 = reinterpret_cast<float4*>(out + base + 16 * t);
#pragma unroll
    for (int q = 0; q < 4; ++q) {
      float4 o;
      o.x = fmaf(sc[q].x, v[4 * q + 0] * norm, sh[q].x);
      o.y = fmaf(sc[q].y, v[4 * q + 1] * norm, sh[q].y);
      o.z = fmaf(sc[q].z, v[4 * q + 2] * norm, sh[q].z);
      o.w = fmaf(sc[q].w, v[4 * q + 3] * norm, sh[q].w);
      o4[q] = o;
    }
  }
}

extern "C" void kernel_launch(void* const* d_in, const int* in_sizes, int n_in,
                              void* d_out, int out_size, void* d_ws, size_t ws_size,
                              hipStream_t stream) {
  const float* x = (const float*)d_in[0];
  const float* scale = (const float*)d_in[1];
  const float* shift = (const float*)d_in[2];
  float* out = (float*)d_out;

  const int rows = in_sizes[0] / ROW;  // 16384, divisible by RPB
  AdaptiveHadamardTransform_kernel<<<rows / RPB, NT, 0, stream>>>(x, scale, shift, out);
}